// Round 1
// baseline (423.501 us; speedup 1.0000x reference)
//
#include <hip/hip_runtime.h>

#define T_DIM 512
#define B_DIM 64
#define V_DIM 1296
#define S_DIM 30
#define L_DIM 61          // 2*S+1
#define NEGF  (-1e30f)

// stable logaddexp, safe when both args are the -1e30 "-inf" surrogate
__device__ __forceinline__ float lae(float a, float b) {
    float mx = fmaxf(a, b);
    float mn = fminf(a, b);
    return mx + log1pf(expf(mn - mx));
}

__global__ __launch_bounds__(64)
void ctc_alpha_kernel(const float* __restrict__ log_probs,   // (T,B,V)
                      const int*   __restrict__ targets,     // (B*S)
                      const int*   __restrict__ input_lengths,
                      const int*   __restrict__ target_lengths,
                      float*       __restrict__ loss_ws)     // (B)
{
    const int b   = blockIdx.x;
    const int l   = threadIdx.x;          // lattice position, lanes 61..63 are dummies
    const int len = input_lengths[b];
    const int tl  = target_lengths[b];    // == S == 30

    // extended label per lane: even -> blank(0), odd -> targets[b*S + l/2]
    int  lab   = 0;
    bool allow = false;
    if ((l & 1) && l < L_DIM) {
        lab = targets[b * S_DIM + (l >> 1)];
        int prev = (l >= 3) ? targets[b * S_DIM + (l >> 1) - 1] : 0; // blank pad for l==1
        allow = (lab != prev);            // lab != 0 always (gloss ids start at 1)
    }

    const float*  addr    = log_probs + (size_t)b * V_DIM + lab;
    const size_t  strideT = (size_t)B_DIM * V_DIM;

    // t = 0 init
    float alpha = NEGF;
    float lp0 = addr[0];
    if (l <= 1) alpha = lp0;              // alpha0[0]=lp[0,0], alpha0[1]=lp[0,1]

    // depth-8 register prefetch pipeline, statically indexed (no scratch)
    const int PF = 8;
    float buf[PF];
#pragma unroll
    for (int i = 0; i < PF; ++i) {
        int tt = 1 + i;
        buf[i] = (tt < len) ? addr[(size_t)tt * strideT] : 0.f;
    }

    int t = 1;
    while (t < len) {
#pragma unroll
        for (int i = 0; i < PF; ++i) {
            if (t < len) {                // wave-uniform (len is per-block scalar)
                float lp_t = buf[i];
                int   tp   = t + PF;
                buf[i] = (tp < len) ? addr[(size_t)tp * strideT] : 0.f;

                float prev1 = __shfl_up(alpha, 1);
                float prev2 = __shfl_up(alpha, 2);
                if (l < 1) prev1 = NEGF;
                if (l < 2) prev2 = NEGF;

                float m  = lae(alpha, prev1);
                float m2 = lae(m, prev2);
                m = allow ? m2 : m;
                alpha = m + lp_t;
                ++t;
            }
        }
    }

    // loss_b = -logaddexp(alpha[2*tl], alpha[2*tl-1]) at t = len-1
    float aBlank = __shfl(alpha, 2 * tl);
    float aLab   = __shfl(alpha, 2 * tl - 1);
    if (l == 0) {
        float loss = -lae(aBlank, aLab);
        if (loss >= 1e29f) loss = 0.f;    // zero_infinity
        loss_ws[b] = loss / (float)tl;    // reduction='mean' divides by target_length
    }
}

__global__ __launch_bounds__(64)
void ctc_reduce_kernel(const float* __restrict__ loss_ws, float* __restrict__ out)
{
    float v = loss_ws[threadIdx.x];
#pragma unroll
    for (int off = 32; off >= 1; off >>= 1)
        v += __shfl_xor(v, off);
    if (threadIdx.x == 0) out[0] = v / (float)B_DIM;
}

extern "C" void kernel_launch(void* const* d_in, const int* in_sizes, int n_in,
                              void* d_out, int out_size, void* d_ws, size_t ws_size,
                              hipStream_t stream)
{
    const float* log_probs      = (const float*)d_in[0];
    const int*   targets        = (const int*)  d_in[1];
    const int*   input_lengths  = (const int*)  d_in[2];
    const int*   target_lengths = (const int*)  d_in[3];
    float*       out            = (float*)d_out;
    float*       ws             = (float*)d_ws;   // 64 floats of scratch

    hipLaunchKernelGGL(ctc_alpha_kernel, dim3(B_DIM), dim3(64), 0, stream,
                       log_probs, targets, input_lengths, target_lengths, ws);
    hipLaunchKernelGGL(ctc_reduce_kernel, dim3(1), dim3(64), 0, stream, ws, out);
}

// Round 2
// 94.125 us; speedup vs baseline: 4.4994x; 4.4994x over previous
//
#include <hip/hip_runtime.h>

#define T_DIM 512
#define B_DIM 64
#define V_DIM 1296
#define S_DIM 30
#define L_DIM 61          // 2*S+1
#define J_DIM 32          // compact row: [blank, lab0..lab29, pad]
#define NEGF  (-1e30f)

// ---------------------------------------------------------------------------
// Kernel 1: massively-parallel gather of the needed log-probs.
// compact[b][t][j]:
//   j==0        -> log_probs[t][b][0]                (blank)
//   j in 1..30  -> log_probs[t][b][targets[b*30+j-1]]
//   j==31       -> blank (pad, value never used but keeps loads in-bounds)
// Total 512*64*32 = 1M elements = 4 MB.
// ---------------------------------------------------------------------------
__global__ __launch_bounds__(256)
void ctc_gather_kernel(const float* __restrict__ log_probs,
                       const int*   __restrict__ targets,
                       float*       __restrict__ compact)
{
    int i = blockIdx.x * 256 + threadIdx.x;      // i < 512*64*32
    int b = i >> 14;                             // / (512*32)
    int t = (i >> 5) & (T_DIM - 1);
    int j = i & 31;
    int lab = 0;
    if (j >= 1 && j <= S_DIM) lab = targets[b * S_DIM + j - 1];
    compact[i] = log_probs[((size_t)t * B_DIM + b) * V_DIM + lab];
}

// fused 3-way log-sum-exp; c == NEGF contributes exp(-inf)=0
__device__ __forceinline__ float lse3(float a, float b, float c) {
    float m = fmaxf(fmaxf(a, b), c);
    float s = __expf(a - m) + __expf(b - m) + __expf(c - m);
    return m + __logf(s);
}
__device__ __forceinline__ float lae(float a, float b) {
    float mx = fmaxf(a, b);
    float mn = fminf(a, b);
    return mx + __logf(1.0f + __expf(mn - mx));
}

// ---------------------------------------------------------------------------
// Kernel 2: serial alpha scan, one wave per batch element, reading compact.
// ---------------------------------------------------------------------------
__global__ __launch_bounds__(64)
void ctc_scan_kernel(const float* __restrict__ compact,      // (B,T,32)
                     const int*   __restrict__ targets,
                     const int*   __restrict__ input_lengths,
                     const int*   __restrict__ target_lengths,
                     float*       __restrict__ loss_ws)
{
    const int b   = blockIdx.x;
    const int l   = threadIdx.x;
    const int len = input_lengths[b];
    const int tl  = target_lengths[b];           // == 30

    // per-lane compact index: even lattice pos -> blank slot 0, odd -> 1+l/2
    const int idx = (l & 1) ? (1 + (l >> 1)) : 0;   // lanes 61..63 hit slots <=31

    bool allow = false;
    if ((l & 1) && l < L_DIM) {
        int lab  = targets[b * S_DIM + (l >> 1)];
        int prev = (l >= 3) ? targets[b * S_DIM + (l >> 1) - 1] : 0;
        allow = (lab != prev);
    }

    const float* base = compact + (size_t)b * T_DIM * J_DIM;

    // t = 0 init
    float alpha = NEGF;
    float lp0 = base[idx];
    if (l <= 1) alpha = lp0;

    // depth-8 register pipeline, static indices, clamped (always-valid) loads
    const int PF = 8;
    float buf[PF];
#pragma unroll
    for (int i = 0; i < PF; ++i)
        buf[i] = base[(size_t)(1 + i) * J_DIM + idx];

    for (int chunk = 0; chunk < T_DIM - 1; chunk += PF) {
        if (chunk + 1 >= len) break;             // wave-uniform early exit
#pragma unroll
        for (int i = 0; i < PF; ++i) {
            int   tt   = chunk + 1 + i;
            float lp_t = buf[i];
            int   tp   = tt + PF; if (tp > T_DIM - 1) tp = T_DIM - 1;
            buf[i] = base[(size_t)tp * J_DIM + idx];

            float prev1 = __shfl_up(alpha, 1);
            float prev2 = __shfl_up(alpha, 2);
            if (l < 1) prev1 = NEGF;
            if (l < 2) prev2 = NEGF;
            float skip = allow ? prev2 : NEGF;

            float na = lse3(alpha, prev1, skip) + lp_t;
            alpha = (tt < len) ? na : alpha;     // freeze past this sample's length
        }
    }

    float aBlank = __shfl(alpha, 2 * tl);
    float aLab   = __shfl(alpha, 2 * tl - 1);
    if (l == 0) {
        float loss = -lae(aBlank, aLab);
        if (loss >= 1e29f) loss = 0.f;           // zero_infinity
        loss_ws[b] = loss / (float)tl;
    }
}

// ---------------------------------------------------------------------------
// Fallback scan (direct gather from log_probs) if ws is too small for compact.
// ---------------------------------------------------------------------------
__global__ __launch_bounds__(64)
void ctc_scan_direct_kernel(const float* __restrict__ log_probs,
                            const int*   __restrict__ targets,
                            const int*   __restrict__ input_lengths,
                            const int*   __restrict__ target_lengths,
                            float*       __restrict__ loss_ws)
{
    const int b   = blockIdx.x;
    const int l   = threadIdx.x;
    const int len = input_lengths[b];
    const int tl  = target_lengths[b];

    int  lab   = 0;
    bool allow = false;
    if ((l & 1) && l < L_DIM) {
        lab = targets[b * S_DIM + (l >> 1)];
        int prev = (l >= 3) ? targets[b * S_DIM + (l >> 1) - 1] : 0;
        allow = (lab != prev);
    }

    const float* addr    = log_probs + (size_t)b * V_DIM + lab;
    const size_t strideT = (size_t)B_DIM * V_DIM;

    float alpha = NEGF;
    float lp0 = addr[0];
    if (l <= 1) alpha = lp0;

    const int PF = 8;
    float buf[PF];
#pragma unroll
    for (int i = 0; i < PF; ++i)
        buf[i] = addr[(size_t)(1 + i) * strideT];

    for (int chunk = 0; chunk < T_DIM - 1; chunk += PF) {
        if (chunk + 1 >= len) break;
#pragma unroll
        for (int i = 0; i < PF; ++i) {
            int   tt   = chunk + 1 + i;
            float lp_t = buf[i];
            int   tp   = tt + PF; if (tp > T_DIM - 1) tp = T_DIM - 1;
            buf[i] = addr[(size_t)tp * strideT];

            float prev1 = __shfl_up(alpha, 1);
            float prev2 = __shfl_up(alpha, 2);
            if (l < 1) prev1 = NEGF;
            if (l < 2) prev2 = NEGF;
            float skip = allow ? prev2 : NEGF;

            float na = lse3(alpha, prev1, skip) + lp_t;
            alpha = (tt < len) ? na : alpha;
        }
    }

    float aBlank = __shfl(alpha, 2 * tl);
    float aLab   = __shfl(alpha, 2 * tl - 1);
    if (l == 0) {
        float loss = -lae(aBlank, aLab);
        if (loss >= 1e29f) loss = 0.f;
        loss_ws[b] = loss / (float)tl;
    }
}

__global__ __launch_bounds__(64)
void ctc_reduce_kernel(const float* __restrict__ loss_ws, float* __restrict__ out)
{
    float v = loss_ws[threadIdx.x];
#pragma unroll
    for (int off = 32; off >= 1; off >>= 1)
        v += __shfl_xor(v, off);
    if (threadIdx.x == 0) out[0] = v / (float)B_DIM;
}

extern "C" void kernel_launch(void* const* d_in, const int* in_sizes, int n_in,
                              void* d_out, int out_size, void* d_ws, size_t ws_size,
                              hipStream_t stream)
{
    const float* log_probs      = (const float*)d_in[0];
    const int*   targets        = (const int*)  d_in[1];
    const int*   input_lengths  = (const int*)  d_in[2];
    const int*   target_lengths = (const int*)  d_in[3];
    float*       out            = (float*)d_out;

    const size_t compactElems = (size_t)B_DIM * T_DIM * J_DIM;   // 1M floats
    const size_t need = compactElems * sizeof(float) + B_DIM * sizeof(float);

    if (ws_size >= need) {
        float* compact = (float*)d_ws;
        float* losses  = compact + compactElems;
        const int nthreads = B_DIM * T_DIM * J_DIM;              // 1048576
        hipLaunchKernelGGL(ctc_gather_kernel, dim3(nthreads / 256), dim3(256), 0, stream,
                           log_probs, targets, compact);
        hipLaunchKernelGGL(ctc_scan_kernel, dim3(B_DIM), dim3(64), 0, stream,
                           compact, targets, input_lengths, target_lengths, losses);
        hipLaunchKernelGGL(ctc_reduce_kernel, dim3(1), dim3(64), 0, stream, losses, out);
    } else {
        float* losses = (float*)d_ws;
        hipLaunchKernelGGL(ctc_scan_direct_kernel, dim3(B_DIM), dim3(64), 0, stream,
                           log_probs, targets, input_lengths, target_lengths, losses);
        hipLaunchKernelGGL(ctc_reduce_kernel, dim3(1), dim3(64), 0, stream, losses, out);
    }
}

// Round 3
// 63.528 us; speedup vs baseline: 6.6663x; 1.4816x over previous
//
#include <hip/hip_runtime.h>

#define T_DIM 512
#define B_DIM 64
#define V_DIM 1296
#define S_DIM 30
#define J_DIM 32
#define NEGF  (-1e30f)
#define LOG2E 1.4426950408889634f
#define LN2   0.6931471805599453f

// ---------------------------------------------------------------------------
// DPP helpers: shift alpha up by one lane (lane l <- lane l-1) in ~2 VALU ops.
// row_shr:1 covers lanes 1-15,17-31,...; lane 16 fixed via row_bcast15.
// Only lanes 0..30 carry live lattice state, so lanes 32/48 need no fix.
// ---------------------------------------------------------------------------
__device__ __forceinline__ float dpp_row_shr1(float src, float old) {
    return __int_as_float(__builtin_amdgcn_update_dpp(
        __float_as_int(old), __float_as_int(src), 0x111, 0xf, 0xf, false));
}
__device__ __forceinline__ float dpp_row_bcast15(float src, float old) {
    return __int_as_float(__builtin_amdgcn_update_dpp(
        __float_as_int(old), __float_as_int(src), 0x142, 0xf, 0xf, false));
}

__device__ __forceinline__ float exp2_hw(float x) { return __builtin_amdgcn_exp2f(x); }
__device__ __forceinline__ float log2_hw(float x) { return __builtin_amdgcn_logf(x); }

// base-2 log-sum-exp
__device__ __forceinline__ float lse2_b2(float a, float b) {
    float mx = fmaxf(a, b), mn = fminf(a, b);
    return mx + log2_hw(1.0f + exp2_hw(mn - mx));
}
__device__ __forceinline__ float lse3_b2(float a, float b, float c) {
    float m = fmaxf(fmaxf(a, b), c);          // fuses to v_max3_f32
    float s = exp2_hw(a - m) + exp2_hw(b - m) + exp2_hw(c - m);
    return m + log2_hw(s);
}

// natural-domain (fallback path only)
__device__ __forceinline__ float lae_nat(float a, float b) {
    float mx = fmaxf(a, b), mn = fminf(a, b);
    return mx + __logf(1.0f + __expf(mn - mx));
}
__device__ __forceinline__ float lse3_nat(float a, float b, float c) {
    float m = fmaxf(fmaxf(a, b), c);
    float s = __expf(a - m) + __expf(b - m) + __expf(c - m);
    return m + __logf(s);
}

// ---------------------------------------------------------------------------
// Kernel 1: gather compact rows. compact[b][t][j] = float2{ lp_blank, lp_label_j }
// pre-scaled by log2(e) so the scan runs in base-2. 8 MB total, coalesced stores.
// ---------------------------------------------------------------------------
__global__ __launch_bounds__(256)
void ctc_gather_kernel(const float* __restrict__ log_probs,
                       const int*   __restrict__ targets,
                       float2*      __restrict__ compact)
{
    int i = blockIdx.x * 256 + threadIdx.x;      // B*T*32 = 1M threads
    int b = i >> 14;
    int t = (i >> 5) & (T_DIM - 1);
    int j = i & 31;
    int lab = (j < S_DIM) ? targets[b * S_DIM + j] : 0;
    const float* row = log_probs + ((size_t)t * B_DIM + b) * V_DIM;
    float lpB = row[0];
    float lpL = row[lab];
    compact[i] = make_float2(lpB * LOG2E, lpL * LOG2E);
}

// ---------------------------------------------------------------------------
// Kernel 2: pair-packed alpha scan. Lane l holds alpha[2l] (a0, blank) and
// alpha[2l+1] (a1, label l). One DPP shift per step; base-2 LSE.
// ---------------------------------------------------------------------------
__global__ __launch_bounds__(64)
void ctc_scan_kernel(const float2* __restrict__ compact,   // (B,T,32)
                     const int*    __restrict__ targets,
                     const int*    __restrict__ input_lengths,
                     const int*    __restrict__ target_lengths,
                     float*        __restrict__ loss_ws)
{
    const int b   = blockIdx.x;
    const int l   = threadIdx.x;
    const int len = input_lengths[b];
    const int tl  = target_lengths[b];           // == 30
    const int j   = l & 31;

    // skip-transition allowed into odd pos 2l+1 (label l) iff label differs
    bool allow = true;                           // l==0: pos1, prev label = blank
    if (l >= 1) {
        allow = (l < S_DIM) ? (targets[b * S_DIM + l] != targets[b * S_DIM + l - 1])
                            : false;             // dummy lanes
    }
    const bool is16 = (l == 16);

    const float2* base = compact + ((size_t)b * T_DIM) * J_DIM + j;

    // t = 0 init: alpha[0] = lpB, alpha[1] = lpL, rest NEG
    float2 lp0 = base[0];
    float a0 = (l == 0) ? lp0.x : NEGF;
    float a1 = (l == 0) ? lp0.y : NEGF;

    // depth-16 register pipeline (static indices)
    const int PF = 16;
    float2 buf[PF];
#pragma unroll
    for (int i = 0; i < PF; ++i)
        buf[i] = base[(size_t)(1 + i) * J_DIM];   // len >= 256 > 16, always valid

    int t = 1;
    while (t + PF <= len) {                       // full, unpredicated chunks
#pragma unroll
        for (int i = 0; i < PF; ++i) {
            float2 lp = buf[i];
            int tp = t + i + PF; if (tp > T_DIM - 1) tp = T_DIM - 1;
            buf[i] = base[(size_t)tp * J_DIM];

            float s   = dpp_row_shr1(a1, NEGF);
            float bc  = dpp_row_bcast15(a1, NEGF);
            float a1m = is16 ? bc : s;            // alpha[2l-1] from lane l-1
            float skip = allow ? a1m : NEGF;
            float na1 = lse3_b2(a1, a0, skip) + lp.y;   // odd pos 2l+1
            float na0 = lse2_b2(a0, a1m) + lp.x;        // even pos 2l (no skip)
            a0 = na0; a1 = na1;
        }
        t += PF;
    }
#pragma unroll
    for (int i = 0; i < PF; ++i) {                // predicated tail (<16 steps)
        if (t + i < len) {
            float2 lp = buf[i];
            float s   = dpp_row_shr1(a1, NEGF);
            float bc  = dpp_row_bcast15(a1, NEGF);
            float a1m = is16 ? bc : s;
            float skip = allow ? a1m : NEGF;
            float na1 = lse3_b2(a1, a0, skip) + lp.y;
            float na0 = lse2_b2(a0, a1m) + lp.x;
            a0 = na0; a1 = na1;
        }
    }

    // loss = -ln2 * lse2_b2(alpha[2*tl], alpha[2*tl-1])
    float aB = __shfl(a0, tl);                    // pos 2*tl  (lane tl, a0)
    float aL = __shfl(a1, tl - 1);                // pos 2*tl-1 (lane tl-1, a1)
    if (l == 0) {
        float loss = -LN2 * lse2_b2(aB, aL);
        if (loss >= 1e29f) loss = 0.f;            // zero_infinity
        loss_ws[b] = loss / (float)tl;
    }
}

// ---------------------------------------------------------------------------
// Fallback: direct scan from log_probs (only if ws too small — not expected).
// ---------------------------------------------------------------------------
__global__ __launch_bounds__(64)
void ctc_scan_direct_kernel(const float* __restrict__ log_probs,
                            const int*   __restrict__ targets,
                            const int*   __restrict__ input_lengths,
                            const int*   __restrict__ target_lengths,
                            float*       __restrict__ loss_ws)
{
    const int b   = blockIdx.x;
    const int l   = threadIdx.x;
    const int len = input_lengths[b];
    const int tl  = target_lengths[b];

    int  lab   = 0;
    bool allow = false;
    if ((l & 1) && l < 2 * S_DIM + 1) {
        lab = targets[b * S_DIM + (l >> 1)];
        int prev = (l >= 3) ? targets[b * S_DIM + (l >> 1) - 1] : 0;
        allow = (lab != prev);
    }
    const float* addr    = log_probs + (size_t)b * V_DIM + lab;
    const size_t strideT = (size_t)B_DIM * V_DIM;

    float alpha = NEGF;
    float lp0 = addr[0];
    if (l <= 1) alpha = lp0;

    const int PF = 8;
    float buf[PF];
#pragma unroll
    for (int i = 0; i < PF; ++i) buf[i] = addr[(size_t)(1 + i) * strideT];

    for (int chunk = 0; chunk < T_DIM - 1; chunk += PF) {
        if (chunk + 1 >= len) break;
#pragma unroll
        for (int i = 0; i < PF; ++i) {
            int   tt   = chunk + 1 + i;
            float lp_t = buf[i];
            int   tp   = tt + PF; if (tp > T_DIM - 1) tp = T_DIM - 1;
            buf[i] = addr[(size_t)tp * strideT];
            float prev1 = __shfl_up(alpha, 1);
            float prev2 = __shfl_up(alpha, 2);
            if (l < 1) prev1 = NEGF;
            if (l < 2) prev2 = NEGF;
            float skip = allow ? prev2 : NEGF;
            float na = lse3_nat(alpha, prev1, skip) + lp_t;
            alpha = (tt < len) ? na : alpha;
        }
    }
    float aB = __shfl(alpha, 2 * tl);
    float aL = __shfl(alpha, 2 * tl - 1);
    if (l == 0) {
        float loss = -lae_nat(aB, aL);
        if (loss >= 1e29f) loss = 0.f;
        loss_ws[b] = loss / (float)tl;
    }
}

__global__ __launch_bounds__(64)
void ctc_reduce_kernel(const float* __restrict__ loss_ws, float* __restrict__ out)
{
    float v = loss_ws[threadIdx.x];
#pragma unroll
    for (int off = 32; off >= 1; off >>= 1)
        v += __shfl_xor(v, off);
    if (threadIdx.x == 0) out[0] = v / (float)B_DIM;
}

extern "C" void kernel_launch(void* const* d_in, const int* in_sizes, int n_in,
                              void* d_out, int out_size, void* d_ws, size_t ws_size,
                              hipStream_t stream)
{
    const float* log_probs      = (const float*)d_in[0];
    const int*   targets        = (const int*)  d_in[1];
    const int*   input_lengths  = (const int*)  d_in[2];
    const int*   target_lengths = (const int*)  d_in[3];
    float*       out            = (float*)d_out;

    const size_t compactElems = (size_t)B_DIM * T_DIM * J_DIM;     // 1M float2
    const size_t need = compactElems * sizeof(float2) + B_DIM * sizeof(float);

    if (ws_size >= need) {
        float2* compact = (float2*)d_ws;
        float*  losses  = (float*)(compact + compactElems);
        hipLaunchKernelGGL(ctc_gather_kernel, dim3((B_DIM * T_DIM * J_DIM) / 256),
                           dim3(256), 0, stream, log_probs, targets, compact);
        hipLaunchKernelGGL(ctc_scan_kernel, dim3(B_DIM), dim3(64), 0, stream,
                           compact, targets, input_lengths, target_lengths, losses);
        hipLaunchKernelGGL(ctc_reduce_kernel, dim3(1), dim3(64), 0, stream, losses, out);
    } else {
        float* losses = (float*)d_ws;
        hipLaunchKernelGGL(ctc_scan_direct_kernel, dim3(B_DIM), dim3(64), 0, stream,
                           log_probs, targets, input_lengths, target_lengths, losses);
        hipLaunchKernelGGL(ctc_reduce_kernel, dim3(1), dim3(64), 0, stream, losses, out);
    }
}

// Round 4
// 32.368 us; speedup vs baseline: 13.0841x; 1.9627x over previous
//
#include <hip/hip_runtime.h>

#define T_DIM 512
#define B_DIM 64
#define V_DIM 1296
#define S_DIM 30
#define LN2   0.6931471805599453f

// DPP helper (ctrl/masks compile-time). bound_ctrl=true -> lanes with no
// source read 0 (exactly the linear-domain "-inf").
template<int CTRL, bool BC>
__device__ __forceinline__ float dppf(float src, float old) {
    return __int_as_float(__builtin_amdgcn_update_dpp(
        __float_as_int(old), __float_as_int(src), CTRL, 0xF, 0xF, BC));
}

struct ScanSt { float p0, p1; int E; };

// One 32-step chunk of the scaled (linear-domain) CTC forward recursion.
// Lane l holds p0 = alpha[2l] (blank) and p1 = alpha[2l+1] (label l), both
// scaled by 2^E (E wave-uniform). MODE 0: first chunk (t==0 init),
// MODE 1: full, MODE 2: boundary (predicate t < len).
template<int MODE>
__device__ __forceinline__ void consume_chunk(const float2* __restrict__ ringc,
                                              int c, int len, int jl, bool is16,
                                              float skipw, int l, ScanSt& st)
{
    float p0 = st.p0, p1 = st.p1;
    int   E  = st.E;
    float2 buf[8];
#pragma unroll
    for (int i = 0; i < 8; ++i) buf[i] = ringc[i * 32 + jl];
#pragma unroll
    for (int i = 0; i < 32; ++i) {
        float2 w = buf[i & 7];
        if (i + 8 < 32) buf[i & 7] = ringc[(i + 8) * 32 + jl];
        if (MODE == 0 && i == 0) {
            // t = 0 init: alpha0[0] = w.x, alpha0[1] = w.y (lane 0), scaled 2^64
            p0 = (l == 0) ? ldexpf(w.x, 64) : 0.f;
            p1 = (l == 0) ? ldexpf(w.y, 64) : 0.f;
            E = 64;
        } else {
            float shr = dppf<0x111, true >(p1, 0.f);  // lane l <- l-1 (rows); 0/16/32/48 -> 0
            float bcv = dppf<0x142, false>(p1, p1);   // lanes 16-31 <- lane 15
            float p1m = is16 ? bcv : shr;             // alpha[2l-1]
            float np1 = fmaf(skipw, p1m, p0 + p1) * w.y;  // odd pos 2l+1 (with skip)
            float np0 = (p0 + p1m) * w.x;                 // even pos 2l (no skip)
            if (MODE == 2) {
                bool act = (c * 32 + i) < len;
                p0 = act ? np0 : p0;
                p1 = act ? np1 : p1;
            } else {
                p0 = np0; p1 = np1;
            }
        }
        if ((i & 7) == 7) {
            // renorm every 8 steps: re-center max (lanes 0..31) at 2^64.
            float m = fmaxf(p0, p1);
            m = fmaxf(m, dppf<0x111, true >(m, 0.f));
            m = fmaxf(m, dppf<0x112, true >(m, 0.f));
            m = fmaxf(m, dppf<0x114, true >(m, 0.f));
            m = fmaxf(m, dppf<0x118, true >(m, 0.f));
            m = fmaxf(m, dppf<0x142, false>(m, m));   // lane31 = max(lanes 0..31)
            int eb  = (__float_as_int(m) >> 23) & 0xFF;
            int e31 = __builtin_amdgcn_readlane(eb, 31);
            int s   = 191 - e31;                      // (64+127) - biased exp
            p0 = ldexpf(p0, s);                       // exact power-of-2 scaling
            p1 = ldexpf(p1, s);
            E += s;
        }
    }
    st.p0 = p0; st.p1 = p1; st.E = E;
}

// Producer: stage one 32-row chunk of {w_blank, w_label_j} = exp(lp) into LDS.
// Thread p (0..511) owns entries p and p+512 (fixed j = p&31, rows p>>5, p>>5+16).
__device__ __forceinline__ void stage_chunk(int k, int b, int trow, int lab, int p,
                                            const float* __restrict__ lp,
                                            float2* __restrict__ ring)
{
    int t0 = k * 32 + trow;
    const float* r0 = lp + ((size_t)t0 * B_DIM + b) * V_DIM;
    const float* r1 = r0 + (size_t)16 * B_DIM * V_DIM;   // t0 + 16
    float b0 = r0[0], l0 = r0[lab];
    float b1 = r1[0], l1 = r1[lab];
    float2* slot = ring + (size_t)(k & 3) * 1024;
    slot[p]       = make_float2(__expf(b0), __expf(l0));
    slot[p + 512] = make_float2(__expf(b1), __expf(l1));
}

__global__ __launch_bounds__(576)
void ctc_fused_kernel(const float* __restrict__ log_probs,
                      const int*   __restrict__ targets,
                      const int*   __restrict__ input_lengths,
                      const int*   __restrict__ target_lengths,
                      float*       __restrict__ loss_ws)
{
    __shared__ float2 ring[4 * 1024];                 // 4-chunk ring, 32 KB
    const int  b    = blockIdx.x;
    const int  tid  = threadIdx.x;
    const int  len  = input_lengths[b];
    const bool prod = (tid < 512);

    // producer-persistent
    const int j    = tid & 31;
    const int trow = (tid & 511) >> 5;
    int lab = 0;
    // scanner-persistent
    const int l  = tid - 512;                         // lane in scanner wave
    const int jl = tid & 31;
    ScanSt st = {0.f, 0.f, 0};
    float skipw = 0.f;
    bool  is16  = false;

    if (prod) {
        lab = (j < S_DIM) ? targets[b * S_DIM + j] : 0;
        stage_chunk(0, b, trow, lab, tid, log_probs, ring);
        stage_chunk(1, b, trow, lab, tid, log_probs, ring);
        stage_chunk(2, b, trow, lab, tid, log_probs, ring);
    } else {
        is16 = (l == 16);
        bool allow = (l == 0);
        if (l >= 1 && l < S_DIM)
            allow = (targets[b * S_DIM + l] != targets[b * S_DIM + l - 1]);
        skipw = allow ? 1.f : 0.f;
    }
    __syncthreads();

    for (int c = 0; c < 16; ++c) {
        if (prod) {
            if (c < 13) stage_chunk(c + 3, b, trow, lab, tid, log_probs, ring);
        } else {
            const float2* ringc = ring + (size_t)(c & 3) * 1024;
            if (c == 0)                   consume_chunk<0>(ringc, c, len, jl, is16, skipw, l, st);
            else if ((c + 1) * 32 <= len) consume_chunk<1>(ringc, c, len, jl, is16, skipw, l, st);
            else if (c * 32 < len)        consume_chunk<2>(ringc, c, len, jl, is16, skipw, l, st);
        }
        __syncthreads();                              // uniform: every wave, every c
    }

    if (!prod) {
        float pB = __shfl(st.p0, 30);                 // alpha[2*tl]   (pos 60)
        float pL = __shfl(st.p1, 29);                 // alpha[2*tl-1] (pos 59)
        if (l == 0) {
            int   tl   = target_lengths[b];
            float sum  = pB + pL;
            float loss = -LN2 * (__builtin_amdgcn_logf(sum) - (float)st.E);
            if (!(loss < 1e29f)) loss = 0.f;          // zero_infinity (catches inf/NaN)
            loss_ws[b] = loss / (float)tl;
        }
    }
}

__global__ __launch_bounds__(64)
void ctc_reduce_kernel(const float* __restrict__ loss_ws, float* __restrict__ out)
{
    float v = loss_ws[threadIdx.x];
#pragma unroll
    for (int off = 32; off >= 1; off >>= 1)
        v += __shfl_xor(v, off);
    if (threadIdx.x == 0) out[0] = v / (float)B_DIM;
}

extern "C" void kernel_launch(void* const* d_in, const int* in_sizes, int n_in,
                              void* d_out, int out_size, void* d_ws, size_t ws_size,
                              hipStream_t stream)
{
    const float* log_probs      = (const float*)d_in[0];
    const int*   targets        = (const int*)  d_in[1];
    const int*   input_lengths  = (const int*)  d_in[2];
    const int*   target_lengths = (const int*)  d_in[3];
    float*       out            = (float*)d_out;
    float*       losses         = (float*)d_ws;       // 64 floats of scratch

    hipLaunchKernelGGL(ctc_fused_kernel, dim3(B_DIM), dim3(576), 0, stream,
                       log_probs, targets, input_lengths, target_lengths, losses);
    hipLaunchKernelGGL(ctc_reduce_kernel, dim3(1), dim3(64), 0, stream, losses, out);
}